// Round 17
// baseline (19684.422 us; speedup 1.0000x reference)
//
#include <hip/hip_runtime.h>

#define NWG   256
#define TPB_R 256
#define TPB_S 1024
#define NSTEP 1000
#define NDATA 2048
#define WIDTH 4096

typedef __attribute__((ext_vector_type(4))) float f32x4;
typedef __attribute__((ext_vector_type(2))) float f32x2;
typedef __attribute__((ext_vector_type(2))) unsigned int u32x2;
typedef __attribute__((ext_vector_type(4))) unsigned int u32x4;
typedef unsigned int uint;

#define SCHED_FENCE() __builtin_amdgcn_sched_barrier(0)

// ---------- scalar helpers ----------

__device__ __forceinline__ float sp_f(float v) {
  return fmaxf(v, 0.0f) + log1pf(expf(-fabsf(v)));
}

__device__ __forceinline__ float wred(float v) {
#pragma unroll
  for (int m = 32; m > 0; m >>= 1) v += __shfl_xor(v, m, 64);
  return v;
}

__device__ __forceinline__ uint pk_bf16(float lo, float hi) {
  uint r;
  asm("v_cvt_pk_bf16_f32 %0, %1, %2" : "=v"(r) : "v"(lo), "v"(hi));
  return r;
}

// ---------- waits / barriers ----------

__device__ __forceinline__ void wait_vm0()   { asm volatile("s_waitcnt vmcnt(0)" ::: "memory"); SCHED_FENCE(); }
template<int N>
__device__ __forceinline__ void wait_vmN()   { asm volatile("s_waitcnt vmcnt(%0)" :: "n"(N) : "memory"); SCHED_FENCE(); }
__device__ __forceinline__ void wait_lgkm0() { asm volatile("s_waitcnt lgkmcnt(0)" ::: "memory"); SCHED_FENCE(); }
__device__ __forceinline__ void wgbar()      { __builtin_amdgcn_s_barrier(); SCHED_FENCE(); }

// ---------- L2-bypass (IC-coherent) I/O ----------

__device__ __forceinline__ void st_sc_x1(float* p, float v) {
  asm volatile("global_store_dword %0, %1, off sc0 sc1" :: "v"(p), "v"(v) : "memory");
}
__device__ __forceinline__ void st_sc_x2(float* p, f32x2 v) {
  asm volatile("global_store_dwordx2 %0, %1, off sc0 sc1" :: "v"(p), "v"(v) : "memory");
}
__device__ __forceinline__ void st_sc_u2(uint* p, u32x2 v) {
  asm volatile("global_store_dwordx2 %0, %1, off sc0 sc1" :: "v"(p), "v"(v) : "memory");
}
__device__ __forceinline__ void ld_sc_x2_issue(const float* p, f32x2& v) {
  asm volatile("global_load_dwordx2 %0, %1, off sc0 sc1" : "=v"(v) : "v"(p) : "memory");
}
__device__ __forceinline__ void ld_sc_x4_issue(const f32x4* p, f32x4& v) {
  asm volatile("global_load_dwordx4 %0, %1, off sc0 sc1" : "=v"(v) : "v"(p) : "memory");
}
__device__ __forceinline__ void ld_sc_u4_issue(const u32x4* p, u32x4& v) {
  asm volatile("global_load_dwordx4 %0, %1, off sc0 sc1" : "=v"(v) : "v"(p) : "memory");
}
__device__ __forceinline__ void ld_sc_x1_issue(const float* p, float& v) {
  asm volatile("global_load_dword %0, %1, off sc0 sc1" : "=v"(v) : "v"(p) : "memory");
}
__device__ __forceinline__ uint ld_sc_u32(const uint* p) {
  uint v;
  asm volatile("global_load_dword %0, %1, off sc0 sc1\n\ts_waitcnt vmcnt(0)"
               : "=v"(v) : "v"(p) : "memory");
  return v;
}
__device__ __forceinline__ void st_sc_u32(uint* p, uint v) {
  asm volatile("global_store_dword %0, %1, off sc0 sc1" :: "v"(p), "v"(v) : "memory");
}
__device__ __forceinline__ void ld_g(const u32x4* p, u32x4& v) {
  asm volatile("global_load_dwordx4 %0, %1, off" : "=v"(v) : "v"(p) : "memory");
}

// ---------- FUSED grid-barrier + activation stage (bf16 exchange) ----------

__device__ __forceinline__ void sync_stage_h(uint* flags, uint tag, int wg,
                                             int tid, const uint* src,
                                             uint* xs) {
  wgbar();
  if (tid == 0) st_sc_u32(flags + wg * 16, tag);
  const uint* fp = flags + tid * 16;
  if (ld_sc_u32(fp) < tag) {
    do { __builtin_amdgcn_s_sleep(1); } while (ld_sc_u32(fp) < tag);
  }
  const u32x4* s = (const u32x4*)src + tid * 2;
  u32x4 a, b;
  ld_sc_u4_issue(s + 0, a); ld_sc_u4_issue(s + 1, b);
  wait_vm0();
  u32x4* l = (u32x4*)xs + tid * 2;
  l[0] = a; l[1] = b;
  wait_lgkm0();
  wgbar();
}

__device__ __forceinline__ void sync_stage_y(uint* flags, uint tag, int wg,
                                             int tid, const float* src,
                                             uint* xs) {
  wgbar();
  if (tid == 0) st_sc_u32(flags + wg * 16, tag);
  const uint* fp = flags + tid * 16;
  if (ld_sc_u32(fp) < tag) {
    do { __builtin_amdgcn_s_sleep(1); } while (ld_sc_u32(fp) < tag);
  }
  const f32x4* s = (const f32x4*)src + tid * 2;
  f32x4 a, b;
  ld_sc_x4_issue(s + 0, a); ld_sc_x4_issue(s + 1, b);
  wait_vm0();
  u32x4 o;
  o.x = pk_bf16(a.x, a.y); o.y = pk_bf16(a.z, a.w);
  o.z = pk_bf16(b.x, b.y); o.w = pk_bf16(b.z, b.w);
  ((u32x4*)xs)[tid] = o;
  wait_lgkm0();
  wgbar();
}

// plain stage of a 2048-f32 input vector (d_in, always visible) -> bf16 LDS
__device__ __forceinline__ void stage_plain_2048(const float* src, uint* xs, int tid) {
  wgbar();
  const f32x4* s = (const f32x4*)src + tid * 2;
  f32x4 a = s[0], b = s[1];
  u32x4 o;
  o.x = pk_bf16(a.x, a.y); o.y = pk_bf16(a.z, a.w);
  o.z = pk_bf16(b.x, b.y); o.w = pk_bf16(b.z, b.w);
  ((u32x4*)xs)[tid] = o;
  wait_lgkm0();
  wgbar();
}

// ---------- fp32 -> permuted bf16 u32x4 chunks (weights) ----------

__device__ __forceinline__ uint bfr(float f) {
  uint u = __float_as_uint(f);
  return (u + 0x7fffu + ((u >> 16) & 1u)) >> 16;
}

__global__ void cvt_perm(const float* __restrict__ in, u32x4* __restrict__ out,
                         int rows, int K) {
  int idx = blockIdx.x * 256 + threadIdx.x;
  int cpr = K >> 3;
  if (idx >= rows * cpr) return;
  int row = idx / cpr, c = idx - row * cpr;
  int j = c >> 6, lane = c & 63;
  const f32x4* p = (const f32x4*)(in + (size_t)row * K + j * 512 + lane * 4);
  f32x4 lo = p[0];
  f32x4 hi = p[64];
  u32x4 o;
  o.x = bfr(lo.x) | (bfr(lo.y) << 16);
  o.y = bfr(lo.z) | (bfr(lo.w) << 16);
  o.z = bfr(hi.x) | (bfr(hi.y) << 16);
  o.w = bfr(hi.z) | (bfr(hi.w) << 16);
  out[idx] = o;
}

// ---------- dot macro: v_dot2_f32_bf16 ----------

#define VD(W, X, s) asm("v_dot2_f32_bf16 %0, %1, %2, %0" : "+v"(s) : "v"(W), "v"(X))

// ---------- one-time GEMM v2: G = W0 @ W3, bf16 dot2, 128x64 tiles ----------

__global__ void __launch_bounds__(256) gemm_G2(const float* __restrict__ W0,
                                               const float* __restrict__ W3,
                                               uint* __restrict__ Gp) {
  __shared__ uint As[16][128];   // 8 KB
  __shared__ uint Bs[16][64];    // 4 KB
  const int bid = blockIdx.x;
  const int tm = bid >> 6, tn = bid & 63;       // 32 x 64 tile grid
  const int r0 = tm * 128, c0 = tn * 64;
  const int tid = threadIdx.x;
  const int m0 = (tid >> 4) * 8, n0 = (tid & 15) * 4;
  float acc[8][4] = {};
  for (int kb = 0; kb < 2048; kb += 32) {
    __syncthreads();
    {
      int row = tid >> 1, ks = (tid & 1) * 16;
      const f32x4* src = (const f32x4*)(W0 + (size_t)(r0 + row) * 2048 + kb + ks);
      f32x4 v0 = src[0], v1 = src[1], v2 = src[2], v3 = src[3];
      int kp = ks >> 1;
      As[kp + 0][row] = pk_bf16(v0.x, v0.y); As[kp + 1][row] = pk_bf16(v0.z, v0.w);
      As[kp + 2][row] = pk_bf16(v1.x, v1.y); As[kp + 3][row] = pk_bf16(v1.z, v1.w);
      As[kp + 4][row] = pk_bf16(v2.x, v2.y); As[kp + 5][row] = pk_bf16(v2.z, v2.w);
      As[kp + 6][row] = pk_bf16(v3.x, v3.y); As[kp + 7][row] = pk_bf16(v3.z, v3.w);
    }
    {
      int kp = tid >> 4, nn = (tid & 15) * 4;
      const f32x4* s0 = (const f32x4*)(W3 + (size_t)(kb + 2 * kp) * 4096 + c0 + nn);
      const f32x4* s1 = (const f32x4*)(W3 + (size_t)(kb + 2 * kp + 1) * 4096 + c0 + nn);
      f32x4 a = s0[0], b = s1[0];
      Bs[kp][nn + 0] = pk_bf16(a.x, b.x);
      Bs[kp][nn + 1] = pk_bf16(a.y, b.y);
      Bs[kp][nn + 2] = pk_bf16(a.z, b.z);
      Bs[kp][nn + 3] = pk_bf16(a.w, b.w);
    }
    __syncthreads();
#define G4(av, r) do{ VD(av, bq.x, acc[r][0]); VD(av, bq.y, acc[r][1]); \
                      VD(av, bq.z, acc[r][2]); VD(av, bq.w, acc[r][3]); }while(0)
#pragma unroll
    for (int kp = 0; kp < 16; ++kp) {
      u32x4 a0 = *(const u32x4*)&As[kp][m0];
      u32x4 a1 = *(const u32x4*)&As[kp][m0 + 4];
      u32x4 bq = *(const u32x4*)&Bs[kp][n0];
      G4(a0.x, 0); G4(a0.y, 1); G4(a0.z, 2); G4(a0.w, 3);
      G4(a1.x, 4); G4(a1.y, 5); G4(a1.z, 6); G4(a1.w, 7);
    }
#undef G4
  }
#pragma unroll
  for (int i = 0; i < 8; ++i) {
    int r = r0 + m0 + i;
    int c = c0 + n0;                         // 4-aligned
    int j = c >> 9, q = c & 511;
    int lane, w;
    if (q < 256) { lane = q >> 2; w = 0; } else { lane = (q - 256) >> 2; w = 2; }
    uint* dst = Gp + ((size_t)r * 512 + (size_t)j * 64 + lane) * 4 + w;
    u32x2 v;
    v.x = bfr(acc[i][0]) | (bfr(acc[i][1]) << 16);
    v.y = bfr(acc[i][2]) | (bfr(acc[i][3]) << 16);
    *(u32x2*)dst = v;
  }
}

// ---------- runtime dot macros ----------

#define QF(Q, s) do{                                                 \
  VD((Q).x, xa2.x, s); VD((Q).y, xa2.y, s);                          \
  VD((Q).z, xb2.x, s); VD((Q).w, xb2.y, s);                          \
}while(0)

#define DC(Q, j, s) do{                                              \
  u32x2 xa2 = xw2[(j)*128 + lane];                                   \
  u32x2 xb2 = xw2[(j)*128 + 64 + lane];                              \
  QF(Q, s);                                                          \
}while(0)

#define DL4(j) do{                                                   \
  u32x2 xa2 = xw2[(j)*128 + lane];                                   \
  u32x2 xb2 = xw2[(j)*128 + 64 + lane];                              \
  u32x4 Q0 = w1p[0*512 + (j)*64 + lane];                             \
  u32x4 Q1 = w1p[1*512 + (j)*64 + lane];                             \
  u32x4 Q2 = w1p[2*512 + (j)*64 + lane];                             \
  u32x4 Q3 = w1p[3*512 + (j)*64 + lane];                             \
  QF(Q0, s0); QF(Q1, s1); QF(Q2, s2); QF(Q3, s3);                    \
}while(0)

#define DR4(j, Qa, Qb, Qc, Qd) do{                                   \
  u32x2 xa2 = xw2[(j)*128 + lane];                                   \
  u32x2 xb2 = xw2[(j)*128 + 64 + lane];                              \
  QF(Qa, s0); QF(Qb, s1); QF(Qc, s2); QF(Qd, s3);                    \
}while(0)

#define DR2(j, Qa, Qb) do{                                           \
  u32x2 xa2 = xw2[(j)*128 + lane];                                   \
  u32x2 xb2 = xw2[(j)*128 + 64 + lane];                              \
  QF(Qa, s0); QF(Qb, s1);                                            \
}while(0)

#define SREG(x) __int_as_float(__builtin_amdgcn_readfirstlane(__float_as_int(x)))

// ======================================================================
// FUSED-RESIDENT kernel: 3 grid syncs per step. u := W0·y in registers;
// u' = u + dt(G·h2 + W0·b3). G chunk-0 of each row in LDS (16 KB) so the
// L2-streamed remainder is 3.5 MB/XCD (< 4 MB capacity — r16's 2 MB/step
// FETCH was G thrashing at exactly-capacity, adding HBM-latency jitter
// to phase 3's tail).
// ======================================================================

__global__ void __launch_bounds__(TPB_R, 1) ode_fused(
    const float* __restrict__ ts, const float* __restrict__ y0,
    const u32x4* __restrict__ W0p, const float* __restrict__ b0,
    const u32x4* __restrict__ W1p, const float* __restrict__ b1,
    const u32x4* __restrict__ W2p, const float* __restrict__ b2,
    const u32x4* __restrict__ W3p, const float* __restrict__ b3,
    const u32x4* __restrict__ Gp,
    float* __restrict__ out, uint* x1buf, uint* h1buf, uint* h2buf,
    uint* flags)
{
  __shared__ u32x4 W1lds[16 * 512];   // 128 KB
  __shared__ u32x4 GL1[16 * 64];      // 16 KB: chunk 0 of each WG G row
  __shared__ uint xs[2048];           // 8 KB
  const int wg = blockIdx.x, tid = threadIdx.x;
  const int wave = tid >> 6, lane = tid & 63;
  const float dt = ts[1] - ts[0];
  const int rw = wg * 16 + wave * 4;
  const int rf = wg * 8 + wave * 2;
  const u32x2* xw2 = (const u32x2*)xs;
  const u32x4* w1p = &W1lds[(wave * 4) * 512];

#pragma unroll
  for (int k = 0; k < 32; ++k)
    W1lds[k * 256 + tid] = W1p[(size_t)wg * 8192 + k * 256 + tid];
#pragma unroll
  for (int k = 0; k < 4; ++k) {
    int i = k * 256 + tid;              // row = i>>6, lane = i&63
    GL1[i] = Gp[(size_t)(wg * 16 + (i >> 6)) * 512 + (i & 63)];
  }

#define L2W(r,j) W2p[(size_t)(rw+(r))*512 + (j)*64 + lane]
  u32x4 C00=L2W(0,0),C01=L2W(0,1),C02=L2W(0,2),C03=L2W(0,3),C04=L2W(0,4),C05=L2W(0,5),C06=L2W(0,6),C07=L2W(0,7);
  u32x4 C10=L2W(1,0),C11=L2W(1,1),C12=L2W(1,2),C13=L2W(1,3),C14=L2W(1,4),C15=L2W(1,5),C16=L2W(1,6),C17=L2W(1,7);
  u32x4 C20=L2W(2,0),C21=L2W(2,1),C22=L2W(2,2),C23=L2W(2,3),C24=L2W(2,4),C25=L2W(2,5),C26=L2W(2,6),C27=L2W(2,7);
  u32x4 C30=L2W(3,0),C31=L2W(3,1),C32=L2W(3,2),C33=L2W(3,3),C34=L2W(3,4),C35=L2W(3,5),C36=L2W(3,6),C37=L2W(3,7);
#define L3W(r,j) W3p[(size_t)(rf+(r))*512 + (j)*64 + lane]
  u32x4 D00=L3W(0,0),D01=L3W(0,1),D02=L3W(0,2),D03=L3W(0,3),D04=L3W(0,4),D05=L3W(0,5),D06=L3W(0,6),D07=L3W(0,7);
  u32x4 D10=L3W(1,0),D11=L3W(1,1),D12=L3W(1,2),D13=L3W(1,3),D14=L3W(1,4),D15=L3W(1,5),D16=L3W(1,6),D17=L3W(1,7);

  const float b00=SREG(b0[rw]), b01=SREG(b0[rw+1]), b02=SREG(b0[rw+2]), b03=SREG(b0[rw+3]);
  const float b10=SREG(b1[rw]), b11=SREG(b1[rw+1]), b12=SREG(b1[rw+2]), b13=SREG(b1[rw+3]);
  const float b20=SREG(b2[rw]), b21=SREG(b2[rw+1]), b22=SREG(b2[rw+2]), b23=SREG(b2[rw+3]);
  const float b30=SREG(b3[rf]), b31=SREG(b3[rf+1]);

  wait_vm0(); wait_lgkm0();
  wgbar();

  u32x4 F00,F01,F02,F03,F04,F05,F06,F07, F10,F11,F12,F13,F14,F15,F16,F17;
#define ISSW0ALL() do{                                                         \
  const u32x4* p0_ = W0p + (size_t)(rw+0)*256 + lane;                          \
  const u32x4* p1_ = W0p + (size_t)(rw+1)*256 + lane;                          \
  const u32x4* p2_ = W0p + (size_t)(rw+2)*256 + lane;                          \
  const u32x4* p3_ = W0p + (size_t)(rw+3)*256 + lane;                          \
  ld_g(p0_,F00); ld_g(p0_+64,F01); ld_g(p0_+128,F02); ld_g(p0_+192,F03);       \
  ld_g(p1_,F04); ld_g(p1_+64,F05); ld_g(p1_+128,F06); ld_g(p1_+192,F07);       \
  ld_g(p2_,F10); ld_g(p2_+64,F11); ld_g(p2_+128,F12); ld_g(p2_+192,F13);       \
  ld_g(p3_,F14); ld_g(p3_+64,F15); ld_g(p3_+128,F16); ld_g(p3_+192,F17);       \
}while(0)

  float c0, c1, c2, c3, u0, u1, u2, u3;
  stage_plain_2048(b3, xs, tid);
  ISSW0ALL(); wait_vm0();
  c0=0.f; DC(F00,0,c0); DC(F01,1,c0); DC(F02,2,c0); DC(F03,3,c0);
  c1=0.f; DC(F04,0,c1); DC(F05,1,c1); DC(F06,2,c1); DC(F07,3,c1);
  c2=0.f; DC(F10,0,c2); DC(F11,1,c2); DC(F12,2,c2); DC(F13,3,c2);
  c3=0.f; DC(F14,0,c3); DC(F15,1,c3); DC(F16,2,c3); DC(F17,3,c3);
  c0 = wred(c0); c1 = wred(c1); c2 = wred(c2); c3 = wred(c3);

  stage_plain_2048(y0, xs, tid);
  ISSW0ALL(); wait_vm0();
  u0=0.f; DC(F00,0,u0); DC(F01,1,u0); DC(F02,2,u0); DC(F03,3,u0);
  u1=0.f; DC(F04,0,u1); DC(F05,1,u1); DC(F06,2,u1); DC(F07,3,u1);
  u2=0.f; DC(F10,0,u2); DC(F11,1,u2); DC(F12,2,u2); DC(F13,3,u2);
  u3=0.f; DC(F14,0,u3); DC(F15,1,u3); DC(F16,2,u3); DC(F17,3,u3);
  u0 = wred(u0); u1 = wred(u1); u2 = wred(u2); u3 = wred(u3);

  float yv0 = y0[rf], yv1 = y0[rf + 1];

  if (lane == 0) {
    u32x2 xv;
    xv.x = pk_bf16(sp_f(u0 + b00), sp_f(u1 + b01));
    xv.y = pk_bf16(sp_f(u2 + b02), sp_f(u3 + b03));
    st_sc_u2(x1buf + (rw >> 1), xv);
  }
  wait_vm0();

  // G stream: chunks 1..7 of one row (chunk 0 is LDS-resident in GL1)
#define ISSG7(r, Q1,Q2,Q3,Q4,Q5,Q6,Q7) do{                                     \
  const u32x4* p_ = Gp + (size_t)(rw+(r))*512 + lane;                          \
  ld_g(p_+64,Q1); ld_g(p_+128,Q2); ld_g(p_+192,Q3);                            \
  ld_g(p_+256,Q4); ld_g(p_+320,Q5); ld_g(p_+448,Q7); ld_g(p_+384,Q6);          \
}while(0)
  // G chunk-0 dot from LDS (j = 0)
#define DCL1(r, s) do{                                                         \
  u32x2 xa2 = xw2[lane];                                                       \
  u32x2 xb2 = xw2[64 + lane];                                                  \
  u32x4 Q = GL1[(wave * 4 + (r)) * 64 + lane];                                 \
  QF(Q, s);                                                                    \
}while(0)

  uint tag = 1;
  for (int step = 0; step < NSTEP; ++step) {
    float s0, s1, s2, s3;
    // ---- sync1: x1 broadcast; L1 (W1 in LDS) ----
    sync_stage_h(flags, tag, wg, tid, x1buf, xs); ++tag;
    s0=0.f; s1=0.f; s2=0.f; s3=0.f;
    DL4(0); DL4(1); DL4(2); DL4(3); DL4(4); DL4(5); DL4(6); DL4(7);
    s0 = wred(s0); s1 = wred(s1); s2 = wred(s2); s3 = wred(s3);
    if (lane == 0) {
      u32x2 v; v.x = pk_bf16(sp_f(s0+b10), sp_f(s1+b11));
               v.y = pk_bf16(sp_f(s2+b12), sp_f(s3+b13));
      st_sc_u2(h1buf + (rw >> 1), v);
    }
    wait_vm0();

    // ---- sync2: h1 broadcast; L2 (W2 in regs) ----
    sync_stage_h(flags, tag, wg, tid, h1buf, xs); ++tag;
    s0=0.f; s1=0.f; s2=0.f; s3=0.f;
    DR4(0, C00, C10, C20, C30); DR4(1, C01, C11, C21, C31);
    DR4(2, C02, C12, C22, C32); DR4(3, C03, C13, C23, C33);
    DR4(4, C04, C14, C24, C34); DR4(5, C05, C15, C25, C35);
    DR4(6, C06, C16, C26, C36); DR4(7, C07, C17, C27, C37);
    s0 = wred(s0); s1 = wred(s1); s2 = wred(s2); s3 = wred(s3);
    if (lane == 0) {
      u32x2 v; v.x = pk_bf16(sp_f(s0+b20), sp_f(s1+b21));
               v.y = pk_bf16(sp_f(s2+b22), sp_f(s3+b23));
      st_sc_u2(h2buf + (rw >> 1), v);
    }
    wait_vm0();

    // ---- G rows 0,1 (chunks 1-7) issued BEFORE sync3 ----
    ISSG7(0, F01,F02,F03,F04,F05,F06,F07);
    ISSG7(1, F11,F12,F13,F14,F15,F16,F17);

    // ---- sync3: h2 broadcast; fused LF+L0' ----
    sync_stage_h(flags, tag, wg, tid, h2buf, xs); ++tag;   // lands G rows 0,1
    float g0=0.f, g1=0.f, g2=0.f, g3=0.f;
    DCL1(0, g0);
    DC(F01,1,g0); DC(F02,2,g0); DC(F03,3,g0);
    DC(F04,4,g0); DC(F05,5,g0); DC(F06,6,g0); DC(F07,7,g0);
    DCL1(1, g1);
    DC(F11,1,g1); DC(F12,2,g1); DC(F13,3,g1);
    DC(F14,4,g1); DC(F15,5,g1); DC(F16,6,g1); DC(F17,7,g1);
    ISSG7(2, F01,F02,F03,F04,F05,F06,F07);
    ISSG7(3, F11,F12,F13,F14,F15,F16,F17);
    s0=0.f; s1=0.f;                       // z = W3·h2 (resident)
    DR2(0, D00, D10); DR2(1, D01, D11); DR2(2, D02, D12); DR2(3, D03, D13);
    DR2(4, D04, D14); DR2(5, D05, D15); DR2(6, D06, D16); DR2(7, D07, D17);
    wait_vm0();                           // G rows 2,3 landed
    DCL1(2, g2);
    DC(F01,1,g2); DC(F02,2,g2); DC(F03,3,g2);
    DC(F04,4,g2); DC(F05,5,g2); DC(F06,6,g2); DC(F07,7,g2);
    DCL1(3, g3);
    DC(F11,1,g3); DC(F12,2,g3); DC(F13,3,g3);
    DC(F14,4,g3); DC(F15,5,g3); DC(F16,6,g3); DC(F17,7,g3);
    g0 = wred(g0); g1 = wred(g1); g2 = wred(g2); g3 = wred(g3);
    s0 = wred(s0); s1 = wred(s1);
    u0 += dt * (g0 + c0); u1 += dt * (g1 + c1);
    u2 += dt * (g2 + c2); u3 += dt * (g3 + c3);
    yv0 += dt * (s0 + b30); yv1 += dt * (s1 + b31);
    float* yout = out + (size_t)step * NDATA;
    if (lane == 0) {
      f32x2 yv; yv.x = yv0; yv.y = yv1;
      st_sc_x2(yout + rf, yv);
      u32x2 xv;
      xv.x = pk_bf16(sp_f(u0 + b00), sp_f(u1 + b01));
      xv.y = pk_bf16(sp_f(u2 + b02), sp_f(u3 + b03));
      st_sc_u2(x1buf + (rw >> 1), xv);
    }
    wait_vm0();
  }
}

// ======================================================================
// FALLBACK A (ws fits bf16 but not G): round-14 kernel, verbatim.
// ======================================================================

__global__ void __launch_bounds__(TPB_R, 1) ode_res(
    const float* __restrict__ ts, const float* __restrict__ y0,
    const u32x4* __restrict__ W0p, const float* __restrict__ b0,
    const u32x4* __restrict__ W1p, const float* __restrict__ b1,
    const u32x4* __restrict__ W2p, const float* __restrict__ b2,
    const u32x4* __restrict__ W3p, const float* __restrict__ b3,
    float* __restrict__ out, uint* hA, uint* hB,
    uint* flags)
{
  __shared__ u32x4 W1lds[16 * 512];
  __shared__ uint xs[2048];
  const int wg = blockIdx.x, tid = threadIdx.x;
  const int wave = tid >> 6, lane = tid & 63;
  const float dt = ts[1] - ts[0];
  const int rw = wg * 16 + wave * 4;
  const int rf = wg * 8 + wave * 2;
  const u32x2* xw2 = (const u32x2*)xs;
  const u32x4* w1p = &W1lds[(wave * 4) * 512];

#pragma unroll
  for (int k = 0; k < 32; ++k)
    W1lds[k * 256 + tid] = W1p[(size_t)wg * 8192 + k * 256 + tid];

  u32x4 C00=L2W(0,0),C01=L2W(0,1),C02=L2W(0,2),C03=L2W(0,3),C04=L2W(0,4),C05=L2W(0,5),C06=L2W(0,6),C07=L2W(0,7);
  u32x4 C10=L2W(1,0),C11=L2W(1,1),C12=L2W(1,2),C13=L2W(1,3),C14=L2W(1,4),C15=L2W(1,5),C16=L2W(1,6),C17=L2W(1,7);
  u32x4 C20=L2W(2,0),C21=L2W(2,1),C22=L2W(2,2),C23=L2W(2,3),C24=L2W(2,4),C25=L2W(2,5),C26=L2W(2,6),C27=L2W(2,7);
  u32x4 C30=L2W(3,0),C31=L2W(3,1),C32=L2W(3,2),C33=L2W(3,3),C34=L2W(3,4),C35=L2W(3,5),C36=L2W(3,6),C37=L2W(3,7);
  u32x4 D00=L3W(0,0),D01=L3W(0,1),D02=L3W(0,2),D03=L3W(0,3),D04=L3W(0,4),D05=L3W(0,5),D06=L3W(0,6),D07=L3W(0,7);
  u32x4 D10=L3W(1,0),D11=L3W(1,1),D12=L3W(1,2),D13=L3W(1,3),D14=L3W(1,4),D15=L3W(1,5),D16=L3W(1,6),D17=L3W(1,7);

  const float b00=SREG(b0[rw]), b01=SREG(b0[rw+1]), b02=SREG(b0[rw+2]), b03=SREG(b0[rw+3]);
  const float b10=SREG(b1[rw]), b11=SREG(b1[rw+1]), b12=SREG(b1[rw+2]), b13=SREG(b1[rw+3]);
  const float b20=SREG(b2[rw]), b21=SREG(b2[rw+1]), b22=SREG(b2[rw+2]), b23=SREG(b2[rw+3]);
  const float b30=SREG(b3[rf]), b31=SREG(b3[rf+1]);

  wait_vm0(); wait_lgkm0();
  wgbar();

  const u32x4* w0base = W0p + (size_t)rw * 256 + lane;
#define ISSW0(r, Qa, Qb, Qc, Qd) do{ const u32x4* p_ = w0base + (size_t)(r)*256; \
  ld_g(p_, Qa); ld_g(p_+64, Qb); ld_g(p_+128, Qc); ld_g(p_+192, Qd); }while(0)

  u32x4 E0a,E0b,E0c,E0d, E1a,E1b,E1c,E1d, E2a,E2b,E2c,E2d, E3a,E3b,E3c,E3d;
  ISSW0(0, E0a,E0b,E0c,E0d);

  uint tag = 0;
  const float* yin = y0;
  for (int step = 0; step < NSTEP; ++step) {
    float s0, s1, s2, s3;
    sync_stage_y(flags, tag, wg, tid, yin, xs); ++tag;
    ISSW0(1, E1a,E1b,E1c,E1d);
    s0 = 0.f; DC(E0a,0,s0); DC(E0b,1,s0); DC(E0c,2,s0); DC(E0d,3,s0);
    ISSW0(2, E2a,E2b,E2c,E2d);
    wait_vmN<4>();
    s1 = 0.f; DC(E1a,0,s1); DC(E1b,1,s1); DC(E1c,2,s1); DC(E1d,3,s1);
    ISSW0(3, E3a,E3b,E3c,E3d);
    wait_vmN<4>();
    s2 = 0.f; DC(E2a,0,s2); DC(E2b,1,s2); DC(E2c,2,s2); DC(E2d,3,s2);
    wait_vm0();
    s3 = 0.f; DC(E3a,0,s3); DC(E3b,1,s3); DC(E3c,2,s3); DC(E3d,3,s3);
    s0 = wred(s0); s1 = wred(s1); s2 = wred(s2); s3 = wred(s3);
    if (lane == 0) {
      u32x2 v; v.x = pk_bf16(sp_f(s0+b00), sp_f(s1+b01));
               v.y = pk_bf16(sp_f(s2+b02), sp_f(s3+b03));
      st_sc_u2(hA + (rw >> 1), v);
    }
    wait_vm0();

    sync_stage_h(flags, tag, wg, tid, hA, xs); ++tag;
    s0=0.f; s1=0.f; s2=0.f; s3=0.f;
    DL4(0); DL4(1); DL4(2); DL4(3); DL4(4); DL4(5); DL4(6); DL4(7);
    s0 = wred(s0); s1 = wred(s1); s2 = wred(s2); s3 = wred(s3);
    if (lane == 0) {
      u32x2 v; v.x = pk_bf16(sp_f(s0+b10), sp_f(s1+b11));
               v.y = pk_bf16(sp_f(s2+b12), sp_f(s3+b13));
      st_sc_u2(hB + (rw >> 1), v);
    }
    wait_vm0();

    sync_stage_h(flags, tag, wg, tid, hB, xs); ++tag;
    s0=0.f; s1=0.f; s2=0.f; s3=0.f;
    DR4(0, C00, C10, C20, C30); DR4(1, C01, C11, C21, C31);
    DR4(2, C02, C12, C22, C32); DR4(3, C03, C13, C23, C33);
    DR4(4, C04, C14, C24, C34); DR4(5, C05, C15, C25, C35);
    DR4(6, C06, C16, C26, C36); DR4(7, C07, C17, C27, C37);
    s0 = wred(s0); s1 = wred(s1); s2 = wred(s2); s3 = wred(s3);
    if (lane == 0) {
      u32x2 v; v.x = pk_bf16(sp_f(s0+b20), sp_f(s1+b21));
               v.y = pk_bf16(sp_f(s2+b22), sp_f(s3+b23));
      st_sc_u2(hA + (rw >> 1), v);
    }
    wait_vm0();

    sync_stage_h(flags, tag, wg, tid, hA, xs); ++tag;
    f32x2 yo;
    ld_sc_x2_issue(yin + rf, yo);
    s0=0.f; s1=0.f;
    DR2(0, D00, D10); DR2(1, D01, D11); DR2(2, D02, D12); DR2(3, D03, D13);
    DR2(4, D04, D14); DR2(5, D05, D15); DR2(6, D06, D16); DR2(7, D07, D17);
    s0 = wred(s0); s1 = wred(s1);
    wait_vm0();
    float* yout = out + (size_t)step * NDATA;
    if (lane == 0) {
      f32x2 v; v.x = yo.x + dt * (s0 + b30); v.y = yo.y + dt * (s1 + b31);
      st_sc_x2(yout + rf, v);
    }
    ISSW0(0, E0a,E0b,E0c,E0d);
    wait_vmN<4>();
    yin = yout;
  }
}

// ======================================================================
// FALLBACK B (ws tiny): fp32 streaming kernel, TPB=1024.
// ======================================================================

__device__ __forceinline__ void gbar1k(uint* flags, uint tag, int wg, int tid) {
  wgbar();
  if (tid == 0) st_sc_u32(flags + wg * 16, tag);
  if (tid < NWG) {
    const uint* fp = flags + tid * 16;
    if (ld_sc_u32(fp) < tag) {
      do { __builtin_amdgcn_s_sleep(1); } while (ld_sc_u32(fp) < tag);
    }
  }
  wgbar();
}

__device__ __forceinline__ void stage4096_1k(const float* src, float* xsf, int tid) {
  f32x4 a;
  ld_sc_x4_issue((const f32x4*)src + tid, a);
  wait_vm0();
  ((f32x4*)xsf)[tid] = a;
  wait_lgkm0();
  wgbar();
}
__device__ __forceinline__ void stage2048_1k(const float* src, float* xsf, int tid) {
  f32x4 a;
  bool act = tid < 512;
  if (act) ld_sc_x4_issue((const f32x4*)src + tid, a);
  wait_vm0();
  if (act) ((f32x4*)xsf)[tid] = a;
  wait_lgkm0();
  wgbar();
}

__device__ __forceinline__ void issue_row_f32(const float* W, size_t elemidx, int lane, f32x4* wr, int ni) {
  const f32x4* p = (const f32x4*)(W + elemidx) + lane;
  for (int i = 0; i < ni; ++i)
    asm volatile("global_load_dwordx4 %0, %1, off" : "=v"(wr[i]) : "v"(p + i * 64) : "memory");
}

template<int NI>
__device__ __forceinline__ float dot_row_f32(const f32x4* wr, const float* xsf, int xoff, int lane) {
  const f32x4* x4 = (const f32x4*)xsf + xoff;
  float a = 0.f;
#pragma unroll
  for (int i = 0; i < NI; ++i) {
    f32x4 xv = x4[i * 64 + lane];
    a = fmaf(wr[i].x, xv.x, a); a = fmaf(wr[i].y, xv.y, a);
    a = fmaf(wr[i].z, xv.z, a); a = fmaf(wr[i].w, xv.w, a);
  }
  return a;
}

__global__ void __launch_bounds__(TPB_S, 1) ode_stream(
    const float* __restrict__ ts, const float* __restrict__ y0,
    const float* __restrict__ W0, const float* __restrict__ b0,
    const float* __restrict__ W1, const float* __restrict__ b1,
    const float* __restrict__ W2, const float* __restrict__ b2,
    const float* __restrict__ W3, const float* __restrict__ b3,
    float* __restrict__ out, float* hA, float* hB,
    uint* flags)
{
  __shared__ float xsf[WIDTH];
  __shared__ float ps[16];
  const int wg = blockIdx.x, tid = threadIdx.x;
  const int wave = tid >> 6, lane = tid & 63;
  const float dt = ts[1] - ts[0];
  const int rw = wg * 16 + wave;
  const int rF = wg * 8 + (wave >> 1);
  const int hf = wave & 1;

  f32x4 w0r[8], w1r[16], w2r[16], w3r[8];
  issue_row_f32(W0, (size_t)rw * NDATA, lane, w0r, 8);

  uint tag = 0;
  const float* yin = y0;
  for (int step = 0; step < NSTEP; ++step) {
    stage2048_1k(yin, xsf, tid);
    float a = wred(dot_row_f32<8>(w0r, xsf, 0, lane));
    if (lane == 0) st_sc_x1(hA + rw, sp_f(a + b0[rw]));
    issue_row_f32(W1, (size_t)rw * WIDTH, lane, w1r, 16);
    wait_vmN<16>();
    gbar1k(flags, ++tag, wg, tid);

    stage4096_1k(hA, xsf, tid);
    a = wred(dot_row_f32<16>(w1r, xsf, 0, lane));
    if (lane == 0) st_sc_x1(hB + rw, sp_f(a + b1[rw]));
    issue_row_f32(W2, (size_t)rw * WIDTH, lane, w2r, 16);
    wait_vmN<16>();
    gbar1k(flags, ++tag, wg, tid);

    stage4096_1k(hB, xsf, tid);
    a = wred(dot_row_f32<16>(w2r, xsf, 0, lane));
    if (lane == 0) st_sc_x1(hA + rw, sp_f(a + b2[rw]));
    issue_row_f32(W3, (size_t)rF * WIDTH + (size_t)hf * 2048, lane, w3r, 8);
    wait_vmN<8>();
    gbar1k(flags, ++tag, wg, tid);

    stage4096_1k(hA, xsf, tid);
    float yo;
    ld_sc_x1_issue(yin + rF, yo);
    a = wred(dot_row_f32<8>(w3r, xsf, hf * 512, lane));
    if (lane == 0) ps[wave] = a;
    wait_lgkm0();
    wgbar();
    wait_vm0();
    float* yout = out + (size_t)step * NDATA;
    if (hf == 0 && lane == 0) {
      float tot = ps[wave] + ps[wave + 1];
      st_sc_x1(yout + rF, yo + dt * (tot + b3[rF]));
    }
    issue_row_f32(W0, (size_t)rw * NDATA, lane, w0r, 8);
    wait_vmN<8>();
    gbar1k(flags, ++tag, wg, tid);
    yin = yout;
  }
}

// ---------- launch ----------

#define WS_X1   0
#define WS_H1   8192
#define WS_H2   16384
#define WS_CNT  32768
#define WS_WB   65536
static const size_t N_W0 = (size_t)WIDTH * NDATA;   // 8.39M elems
static const size_t N_W1 = (size_t)WIDTH * WIDTH;   // 16.78M
static const size_t N_W3 = (size_t)NDATA * WIDTH;   // 8.39M
static const size_t N_G  = (size_t)WIDTH * WIDTH;   // 16.78M

extern "C" void kernel_launch(void* const* d_in, const int* in_sizes, int n_in,
                              void* d_out, int out_size, void* d_ws, size_t ws_size,
                              hipStream_t stream) {
  const float* ts = (const float*)d_in[0];
  const float* y0 = (const float*)d_in[1];
  const float* W0 = (const float*)d_in[2];
  const float* b0 = (const float*)d_in[3];
  const float* W1 = (const float*)d_in[4];
  const float* b1 = (const float*)d_in[5];
  const float* W2 = (const float*)d_in[6];
  const float* b2 = (const float*)d_in[7];
  const float* W3 = (const float*)d_in[8];
  const float* b3 = (const float*)d_in[9];
  float* out = (float*)d_out;

  char* ws = (char*)d_ws;
  uint* flags = (uint*)(ws + WS_CNT);

  hipMemsetAsync(ws + WS_CNT, 0, 16384, stream);

  const size_t need_bf  = WS_WB + (N_W0 + 2 * N_W1 + N_W3) * 2;        // ~100.7 MB
  const size_t need_fus = need_bf + N_G * 2;                           // ~134.2 MB

  u32x4* W0p = (u32x4*)(ws + WS_WB);
  u32x4* W1p = W0p + N_W0 / 8;
  u32x4* W2p = W1p + N_W1 / 8;
  u32x4* W3p = W2p + N_W1 / 8;
  u32x4* Gp  = W3p + N_W3 / 8;

  if (ws_size >= need_fus) {
    hipLaunchKernelGGL(cvt_perm, dim3((unsigned)(N_W0 / 8 / 256)), dim3(256), 0, stream, W0, W0p, WIDTH, NDATA);
    hipLaunchKernelGGL(cvt_perm, dim3((unsigned)(N_W1 / 8 / 256)), dim3(256), 0, stream, W1, W1p, WIDTH, WIDTH);
    hipLaunchKernelGGL(cvt_perm, dim3((unsigned)(N_W1 / 8 / 256)), dim3(256), 0, stream, W2, W2p, WIDTH, WIDTH);
    hipLaunchKernelGGL(cvt_perm, dim3((unsigned)(N_W3 / 8 / 256)), dim3(256), 0, stream, W3, W3p, NDATA, WIDTH);
    hipLaunchKernelGGL(gemm_G2, dim3(2048), dim3(256), 0, stream, W0, W3, (uint*)Gp);
    uint* x1b = (uint*)(ws + WS_X1);
    uint* h1b = (uint*)(ws + WS_H1);
    uint* h2b = (uint*)(ws + WS_H2);
    hipLaunchKernelGGL(ode_fused, dim3(NWG), dim3(TPB_R), 0, stream,
                       ts, y0, W0p, b0, W1p, b1, W2p, b2, W3p, b3, Gp,
                       out, x1b, h1b, h2b, flags);
  } else if (ws_size >= need_bf) {
    hipLaunchKernelGGL(cvt_perm, dim3((unsigned)(N_W0 / 8 / 256)), dim3(256), 0, stream, W0, W0p, WIDTH, NDATA);
    hipLaunchKernelGGL(cvt_perm, dim3((unsigned)(N_W1 / 8 / 256)), dim3(256), 0, stream, W1, W1p, WIDTH, WIDTH);
    hipLaunchKernelGGL(cvt_perm, dim3((unsigned)(N_W1 / 8 / 256)), dim3(256), 0, stream, W2, W2p, WIDTH, WIDTH);
    hipLaunchKernelGGL(cvt_perm, dim3((unsigned)(N_W3 / 8 / 256)), dim3(256), 0, stream, W3, W3p, NDATA, WIDTH);
    uint* hA = (uint*)(ws + WS_X1);
    uint* hB = (uint*)(ws + WS_H2);
    hipLaunchKernelGGL(ode_res, dim3(NWG), dim3(TPB_R), 0, stream,
                       ts, y0, W0p, b0, W1p, b1, W2p, b2, W3p, b3,
                       out, hA, hB, flags);
  } else {
    float* hAf = (float*)(ws + WS_X1);
    float* hBf = (float*)(ws + WS_H2);
    hipLaunchKernelGGL(ode_stream, dim3(NWG), dim3(TPB_S), 0, stream,
                       ts, y0, W0, b0, W1, b1, W2, b2, W3, b3,
                       out, hAf, hBf, flags);
  }
}

// Round 18
// 18718.451 us; speedup vs baseline: 1.0516x; 1.0516x over previous
//
#include <hip/hip_runtime.h>

#define NWG   256
#define TPB_R 256
#define TPB_S 1024
#define NSTEP 1000
#define NDATA 2048
#define WIDTH 4096

typedef __attribute__((ext_vector_type(4))) float f32x4;
typedef __attribute__((ext_vector_type(2))) float f32x2;
typedef __attribute__((ext_vector_type(2))) unsigned int u32x2;
typedef __attribute__((ext_vector_type(4))) unsigned int u32x4;
typedef unsigned int uint;

#define SCHED_FENCE() __builtin_amdgcn_sched_barrier(0)

// ---------- scalar helpers ----------

__device__ __forceinline__ float sp_f(float v) {
  return fmaxf(v, 0.0f) + log1pf(expf(-fabsf(v)));
}

__device__ __forceinline__ float wred(float v) {
#pragma unroll
  for (int m = 32; m > 0; m >>= 1) v += __shfl_xor(v, m, 64);
  return v;
}

__device__ __forceinline__ uint pk_bf16(float lo, float hi) {
  uint r;
  asm("v_cvt_pk_bf16_f32 %0, %1, %2" : "=v"(r) : "v"(lo), "v"(hi));
  return r;
}

// ---------- waits / barriers ----------

__device__ __forceinline__ void wait_vm0()   { asm volatile("s_waitcnt vmcnt(0)" ::: "memory"); SCHED_FENCE(); }
template<int N>
__device__ __forceinline__ void wait_vmN()   { asm volatile("s_waitcnt vmcnt(%0)" :: "n"(N) : "memory"); SCHED_FENCE(); }
__device__ __forceinline__ void wait_lgkm0() { asm volatile("s_waitcnt lgkmcnt(0)" ::: "memory"); SCHED_FENCE(); }
__device__ __forceinline__ void wgbar()      { __builtin_amdgcn_s_barrier(); SCHED_FENCE(); }

// ---------- L2-bypass (IC-coherent) I/O ----------

__device__ __forceinline__ void st_sc_x1(float* p, float v) {
  asm volatile("global_store_dword %0, %1, off sc0 sc1" :: "v"(p), "v"(v) : "memory");
}
__device__ __forceinline__ void st_sc_x2(float* p, f32x2 v) {
  asm volatile("global_store_dwordx2 %0, %1, off sc0 sc1" :: "v"(p), "v"(v) : "memory");
}
__device__ __forceinline__ void st_sc_u2(uint* p, u32x2 v) {
  asm volatile("global_store_dwordx2 %0, %1, off sc0 sc1" :: "v"(p), "v"(v) : "memory");
}
__device__ __forceinline__ void ld_sc_x2_issue(const float* p, f32x2& v) {
  asm volatile("global_load_dwordx2 %0, %1, off sc0 sc1" : "=v"(v) : "v"(p) : "memory");
}
__device__ __forceinline__ void ld_sc_x4_issue(const f32x4* p, f32x4& v) {
  asm volatile("global_load_dwordx4 %0, %1, off sc0 sc1" : "=v"(v) : "v"(p) : "memory");
}
__device__ __forceinline__ void ld_sc_u4_issue(const u32x4* p, u32x4& v) {
  asm volatile("global_load_dwordx4 %0, %1, off sc0 sc1" : "=v"(v) : "v"(p) : "memory");
}
__device__ __forceinline__ void ld_sc_x1_issue(const float* p, float& v) {
  asm volatile("global_load_dword %0, %1, off sc0 sc1" : "=v"(v) : "v"(p) : "memory");
}
__device__ __forceinline__ uint ld_sc_u32(const uint* p) {
  uint v;
  asm volatile("global_load_dword %0, %1, off sc0 sc1\n\ts_waitcnt vmcnt(0)"
               : "=v"(v) : "v"(p) : "memory");
  return v;
}
__device__ __forceinline__ void st_sc_u32(uint* p, uint v) {
  asm volatile("global_store_dword %0, %1, off sc0 sc1" :: "v"(p), "v"(v) : "memory");
}
__device__ __forceinline__ void ld_g(const u32x4* p, u32x4& v) {
  asm volatile("global_load_dwordx4 %0, %1, off" : "=v"(v) : "v"(p) : "memory");
}

// ---------- FUSED grid-barrier + activation stage (bf16 exchange) ----------

__device__ __forceinline__ void sync_stage_h(uint* flags, uint tag, int wg,
                                             int tid, const uint* src,
                                             uint* xs) {
  wgbar();
  if (tid == 0) st_sc_u32(flags + wg * 16, tag);
  const uint* fp = flags + tid * 16;
  if (ld_sc_u32(fp) < tag) {
    do { __builtin_amdgcn_s_sleep(1); } while (ld_sc_u32(fp) < tag);
  }
  const u32x4* s = (const u32x4*)src + tid * 2;
  u32x4 a, b;
  ld_sc_u4_issue(s + 0, a); ld_sc_u4_issue(s + 1, b);
  wait_vm0();
  u32x4* l = (u32x4*)xs + tid * 2;
  l[0] = a; l[1] = b;
  wait_lgkm0();
  wgbar();
}

__device__ __forceinline__ void sync_stage_y(uint* flags, uint tag, int wg,
                                             int tid, const float* src,
                                             uint* xs) {
  wgbar();
  if (tid == 0) st_sc_u32(flags + wg * 16, tag);
  const uint* fp = flags + tid * 16;
  if (ld_sc_u32(fp) < tag) {
    do { __builtin_amdgcn_s_sleep(1); } while (ld_sc_u32(fp) < tag);
  }
  const f32x4* s = (const f32x4*)src + tid * 2;
  f32x4 a, b;
  ld_sc_x4_issue(s + 0, a); ld_sc_x4_issue(s + 1, b);
  wait_vm0();
  u32x4 o;
  o.x = pk_bf16(a.x, a.y); o.y = pk_bf16(a.z, a.w);
  o.z = pk_bf16(b.x, b.y); o.w = pk_bf16(b.z, b.w);
  ((u32x4*)xs)[tid] = o;
  wait_lgkm0();
  wgbar();
}

// plain stage of a 2048-f32 input vector (d_in, always visible) -> bf16 LDS
__device__ __forceinline__ void stage_plain_2048(const float* src, uint* xs, int tid) {
  wgbar();
  const f32x4* s = (const f32x4*)src + tid * 2;
  f32x4 a = s[0], b = s[1];
  u32x4 o;
  o.x = pk_bf16(a.x, a.y); o.y = pk_bf16(a.z, a.w);
  o.z = pk_bf16(b.x, b.y); o.w = pk_bf16(b.z, b.w);
  ((u32x4*)xs)[tid] = o;
  wait_lgkm0();
  wgbar();
}

// ---------- fp32 -> permuted bf16 u32x4 chunks (weights) ----------

__device__ __forceinline__ uint bfr(float f) {
  uint u = __float_as_uint(f);
  return (u + 0x7fffu + ((u >> 16) & 1u)) >> 16;
}

__global__ void cvt_perm(const float* __restrict__ in, u32x4* __restrict__ out,
                         int rows, int K) {
  int idx = blockIdx.x * 256 + threadIdx.x;
  int cpr = K >> 3;
  if (idx >= rows * cpr) return;
  int row = idx / cpr, c = idx - row * cpr;
  int j = c >> 6, lane = c & 63;
  const f32x4* p = (const f32x4*)(in + (size_t)row * K + j * 512 + lane * 4);
  f32x4 lo = p[0];
  f32x4 hi = p[64];
  u32x4 o;
  o.x = bfr(lo.x) | (bfr(lo.y) << 16);
  o.y = bfr(lo.z) | (bfr(lo.w) << 16);
  o.z = bfr(hi.x) | (bfr(hi.y) << 16);
  o.w = bfr(hi.z) | (bfr(hi.w) << 16);
  out[idx] = o;
}

// ---------- dot macro: v_dot2_f32_bf16 ----------

#define VD(W, X, s) asm("v_dot2_f32_bf16 %0, %1, %2, %0" : "+v"(s) : "v"(W), "v"(X))

// ---------- one-time GEMM v2: G = W0 @ W3, bf16 dot2, 128x64 tiles ----------

__global__ void __launch_bounds__(256) gemm_G2(const float* __restrict__ W0,
                                               const float* __restrict__ W3,
                                               uint* __restrict__ Gp) {
  __shared__ uint As[16][128];   // 8 KB
  __shared__ uint Bs[16][64];    // 4 KB
  const int bid = blockIdx.x;
  const int tm = bid >> 6, tn = bid & 63;       // 32 x 64 tile grid
  const int r0 = tm * 128, c0 = tn * 64;
  const int tid = threadIdx.x;
  const int m0 = (tid >> 4) * 8, n0 = (tid & 15) * 4;
  float acc[8][4] = {};
  for (int kb = 0; kb < 2048; kb += 32) {
    __syncthreads();
    {
      int row = tid >> 1, ks = (tid & 1) * 16;
      const f32x4* src = (const f32x4*)(W0 + (size_t)(r0 + row) * 2048 + kb + ks);
      f32x4 v0 = src[0], v1 = src[1], v2 = src[2], v3 = src[3];
      int kp = ks >> 1;
      As[kp + 0][row] = pk_bf16(v0.x, v0.y); As[kp + 1][row] = pk_bf16(v0.z, v0.w);
      As[kp + 2][row] = pk_bf16(v1.x, v1.y); As[kp + 3][row] = pk_bf16(v1.z, v1.w);
      As[kp + 4][row] = pk_bf16(v2.x, v2.y); As[kp + 5][row] = pk_bf16(v2.z, v2.w);
      As[kp + 6][row] = pk_bf16(v3.x, v3.y); As[kp + 7][row] = pk_bf16(v3.z, v3.w);
    }
    {
      int kp = tid >> 4, nn = (tid & 15) * 4;
      const f32x4* s0 = (const f32x4*)(W3 + (size_t)(kb + 2 * kp) * 4096 + c0 + nn);
      const f32x4* s1 = (const f32x4*)(W3 + (size_t)(kb + 2 * kp + 1) * 4096 + c0 + nn);
      f32x4 a = s0[0], b = s1[0];
      Bs[kp][nn + 0] = pk_bf16(a.x, b.x);
      Bs[kp][nn + 1] = pk_bf16(a.y, b.y);
      Bs[kp][nn + 2] = pk_bf16(a.z, b.z);
      Bs[kp][nn + 3] = pk_bf16(a.w, b.w);
    }
    __syncthreads();
#define G4(av, r) do{ VD(av, bq.x, acc[r][0]); VD(av, bq.y, acc[r][1]); \
                      VD(av, bq.z, acc[r][2]); VD(av, bq.w, acc[r][3]); }while(0)
#pragma unroll
    for (int kp = 0; kp < 16; ++kp) {
      u32x4 a0 = *(const u32x4*)&As[kp][m0];
      u32x4 a1 = *(const u32x4*)&As[kp][m0 + 4];
      u32x4 bq = *(const u32x4*)&Bs[kp][n0];
      G4(a0.x, 0); G4(a0.y, 1); G4(a0.z, 2); G4(a0.w, 3);
      G4(a1.x, 4); G4(a1.y, 5); G4(a1.z, 6); G4(a1.w, 7);
    }
#undef G4
  }
#pragma unroll
  for (int i = 0; i < 8; ++i) {
    int r = r0 + m0 + i;
    int c = c0 + n0;                         // 4-aligned
    int j = c >> 9, q = c & 511;
    int lane, w;
    if (q < 256) { lane = q >> 2; w = 0; } else { lane = (q - 256) >> 2; w = 2; }
    uint* dst = Gp + ((size_t)r * 512 + (size_t)j * 64 + lane) * 4 + w;
    u32x2 v;
    v.x = bfr(acc[i][0]) | (bfr(acc[i][1]) << 16);
    v.y = bfr(acc[i][2]) | (bfr(acc[i][3]) << 16);
    *(u32x2*)dst = v;
  }
}

// ---------- runtime dot macros ----------

#define QF(Q, s) do{                                                 \
  VD((Q).x, xa2.x, s); VD((Q).y, xa2.y, s);                          \
  VD((Q).z, xb2.x, s); VD((Q).w, xb2.y, s);                          \
}while(0)

#define DC(Q, j, s) do{                                              \
  u32x2 xa2 = xw2[(j)*128 + lane];                                   \
  u32x2 xb2 = xw2[(j)*128 + 64 + lane];                              \
  QF(Q, s);                                                          \
}while(0)

#define DL4(j) do{                                                   \
  u32x2 xa2 = xw2[(j)*128 + lane];                                   \
  u32x2 xb2 = xw2[(j)*128 + 64 + lane];                              \
  u32x4 Q0 = w1p[0*512 + (j)*64 + lane];                             \
  u32x4 Q1 = w1p[1*512 + (j)*64 + lane];                             \
  u32x4 Q2 = w1p[2*512 + (j)*64 + lane];                             \
  u32x4 Q3 = w1p[3*512 + (j)*64 + lane];                             \
  QF(Q0, s0); QF(Q1, s1); QF(Q2, s2); QF(Q3, s3);                    \
}while(0)

#define DR4(j, Qa, Qb, Qc, Qd) do{                                   \
  u32x2 xa2 = xw2[(j)*128 + lane];                                   \
  u32x2 xb2 = xw2[(j)*128 + 64 + lane];                              \
  QF(Qa, s0); QF(Qb, s1); QF(Qc, s2); QF(Qd, s3);                    \
}while(0)

#define DR2(j, Qa, Qb) do{                                           \
  u32x2 xa2 = xw2[(j)*128 + lane];                                   \
  u32x2 xb2 = xw2[(j)*128 + 64 + lane];                              \
  QF(Qa, s0); QF(Qb, s1);                                            \
}while(0)

#define SREG(x) __int_as_float(__builtin_amdgcn_readfirstlane(__float_as_int(x)))

// ======================================================================
// FUSED-RESIDENT kernel (round-16 best configuration, restored):
// 3 grid syncs per step. u := W0·y in registers; u' = u + dt(G·h2 + W0·b3).
// y in registers, out write-only. W1 in LDS, W2/W3 in VGPRs, G L2-streamed.
// ======================================================================

__global__ void __launch_bounds__(TPB_R, 1) ode_fused(
    const float* __restrict__ ts, const float* __restrict__ y0,
    const u32x4* __restrict__ W0p, const float* __restrict__ b0,
    const u32x4* __restrict__ W1p, const float* __restrict__ b1,
    const u32x4* __restrict__ W2p, const float* __restrict__ b2,
    const u32x4* __restrict__ W3p, const float* __restrict__ b3,
    const u32x4* __restrict__ Gp,
    float* __restrict__ out, uint* x1buf, uint* h1buf, uint* h2buf,
    uint* flags)
{
  __shared__ u32x4 W1lds[16 * 512];
  __shared__ uint xs[2048];
  const int wg = blockIdx.x, tid = threadIdx.x;
  const int wave = tid >> 6, lane = tid & 63;
  const float dt = ts[1] - ts[0];
  const int rw = wg * 16 + wave * 4;
  const int rf = wg * 8 + wave * 2;
  const u32x2* xw2 = (const u32x2*)xs;
  const u32x4* w1p = &W1lds[(wave * 4) * 512];

#pragma unroll
  for (int k = 0; k < 32; ++k)
    W1lds[k * 256 + tid] = W1p[(size_t)wg * 8192 + k * 256 + tid];

#define L2W(r,j) W2p[(size_t)(rw+(r))*512 + (j)*64 + lane]
  u32x4 C00=L2W(0,0),C01=L2W(0,1),C02=L2W(0,2),C03=L2W(0,3),C04=L2W(0,4),C05=L2W(0,5),C06=L2W(0,6),C07=L2W(0,7);
  u32x4 C10=L2W(1,0),C11=L2W(1,1),C12=L2W(1,2),C13=L2W(1,3),C14=L2W(1,4),C15=L2W(1,5),C16=L2W(1,6),C17=L2W(1,7);
  u32x4 C20=L2W(2,0),C21=L2W(2,1),C22=L2W(2,2),C23=L2W(2,3),C24=L2W(2,4),C25=L2W(2,5),C26=L2W(2,6),C27=L2W(2,7);
  u32x4 C30=L2W(3,0),C31=L2W(3,1),C32=L2W(3,2),C33=L2W(3,3),C34=L2W(3,4),C35=L2W(3,5),C36=L2W(3,6),C37=L2W(3,7);
#define L3W(r,j) W3p[(size_t)(rf+(r))*512 + (j)*64 + lane]
  u32x4 D00=L3W(0,0),D01=L3W(0,1),D02=L3W(0,2),D03=L3W(0,3),D04=L3W(0,4),D05=L3W(0,5),D06=L3W(0,6),D07=L3W(0,7);
  u32x4 D10=L3W(1,0),D11=L3W(1,1),D12=L3W(1,2),D13=L3W(1,3),D14=L3W(1,4),D15=L3W(1,5),D16=L3W(1,6),D17=L3W(1,7);

  const float b00=SREG(b0[rw]), b01=SREG(b0[rw+1]), b02=SREG(b0[rw+2]), b03=SREG(b0[rw+3]);
  const float b10=SREG(b1[rw]), b11=SREG(b1[rw+1]), b12=SREG(b1[rw+2]), b13=SREG(b1[rw+3]);
  const float b20=SREG(b2[rw]), b21=SREG(b2[rw+1]), b22=SREG(b2[rw+2]), b23=SREG(b2[rw+3]);
  const float b30=SREG(b3[rf]), b31=SREG(b3[rf+1]);

  wait_vm0(); wait_lgkm0();
  wgbar();

  u32x4 F00,F01,F02,F03,F04,F05,F06,F07, F10,F11,F12,F13,F14,F15,F16,F17;
#define ISSW0ALL() do{                                                         \
  const u32x4* p0_ = W0p + (size_t)(rw+0)*256 + lane;                          \
  const u32x4* p1_ = W0p + (size_t)(rw+1)*256 + lane;                          \
  const u32x4* p2_ = W0p + (size_t)(rw+2)*256 + lane;                          \
  const u32x4* p3_ = W0p + (size_t)(rw+3)*256 + lane;                          \
  ld_g(p0_,F00); ld_g(p0_+64,F01); ld_g(p0_+128,F02); ld_g(p0_+192,F03);       \
  ld_g(p1_,F04); ld_g(p1_+64,F05); ld_g(p1_+128,F06); ld_g(p1_+192,F07);       \
  ld_g(p2_,F10); ld_g(p2_+64,F11); ld_g(p2_+128,F12); ld_g(p2_+192,F13);       \
  ld_g(p3_,F14); ld_g(p3_+64,F15); ld_g(p3_+128,F16); ld_g(p3_+192,F17);       \
}while(0)

  float c0, c1, c2, c3, u0, u1, u2, u3;
  stage_plain_2048(b3, xs, tid);
  ISSW0ALL(); wait_vm0();
  c0=0.f; DC(F00,0,c0); DC(F01,1,c0); DC(F02,2,c0); DC(F03,3,c0);
  c1=0.f; DC(F04,0,c1); DC(F05,1,c1); DC(F06,2,c1); DC(F07,3,c1);
  c2=0.f; DC(F10,0,c2); DC(F11,1,c2); DC(F12,2,c2); DC(F13,3,c2);
  c3=0.f; DC(F14,0,c3); DC(F15,1,c3); DC(F16,2,c3); DC(F17,3,c3);
  c0 = wred(c0); c1 = wred(c1); c2 = wred(c2); c3 = wred(c3);

  stage_plain_2048(y0, xs, tid);
  ISSW0ALL(); wait_vm0();
  u0=0.f; DC(F00,0,u0); DC(F01,1,u0); DC(F02,2,u0); DC(F03,3,u0);
  u1=0.f; DC(F04,0,u1); DC(F05,1,u1); DC(F06,2,u1); DC(F07,3,u1);
  u2=0.f; DC(F10,0,u2); DC(F11,1,u2); DC(F12,2,u2); DC(F13,3,u2);
  u3=0.f; DC(F14,0,u3); DC(F15,1,u3); DC(F16,2,u3); DC(F17,3,u3);
  u0 = wred(u0); u1 = wred(u1); u2 = wred(u2); u3 = wred(u3);

  float yv0 = y0[rf], yv1 = y0[rf + 1];

  if (lane == 0) {
    u32x2 xv;
    xv.x = pk_bf16(sp_f(u0 + b00), sp_f(u1 + b01));
    xv.y = pk_bf16(sp_f(u2 + b02), sp_f(u3 + b03));
    st_sc_u2(x1buf + (rw >> 1), xv);
  }
  wait_vm0();

#define ISSG(r, Q0,Q1,Q2,Q3,Q4,Q5,Q6,Q7) do{                                   \
  const u32x4* p_ = Gp + (size_t)(rw+(r))*512 + lane;                          \
  ld_g(p_,Q0); ld_g(p_+64,Q1); ld_g(p_+128,Q2); ld_g(p_+192,Q3);               \
  ld_g(p_+256,Q4); ld_g(p_+320,Q5); ld_g(p_+384,Q6); ld_g(p_+448,Q7);          \
}while(0)

  uint tag = 1;
  for (int step = 0; step < NSTEP; ++step) {
    float s0, s1, s2, s3;
    sync_stage_h(flags, tag, wg, tid, x1buf, xs); ++tag;
    s0=0.f; s1=0.f; s2=0.f; s3=0.f;
    DL4(0); DL4(1); DL4(2); DL4(3); DL4(4); DL4(5); DL4(6); DL4(7);
    s0 = wred(s0); s1 = wred(s1); s2 = wred(s2); s3 = wred(s3);
    if (lane == 0) {
      u32x2 v; v.x = pk_bf16(sp_f(s0+b10), sp_f(s1+b11));
               v.y = pk_bf16(sp_f(s2+b12), sp_f(s3+b13));
      st_sc_u2(h1buf + (rw >> 1), v);
    }
    wait_vm0();

    sync_stage_h(flags, tag, wg, tid, h1buf, xs); ++tag;
    s0=0.f; s1=0.f; s2=0.f; s3=0.f;
    DR4(0, C00, C10, C20, C30); DR4(1, C01, C11, C21, C31);
    DR4(2, C02, C12, C22, C32); DR4(3, C03, C13, C23, C33);
    DR4(4, C04, C14, C24, C34); DR4(5, C05, C15, C25, C35);
    DR4(6, C06, C16, C26, C36); DR4(7, C07, C17, C27, C37);
    s0 = wred(s0); s1 = wred(s1); s2 = wred(s2); s3 = wred(s3);
    if (lane == 0) {
      u32x2 v; v.x = pk_bf16(sp_f(s0+b20), sp_f(s1+b21));
               v.y = pk_bf16(sp_f(s2+b22), sp_f(s3+b23));
      st_sc_u2(h2buf + (rw >> 1), v);
    }
    wait_vm0();

    ISSG(0, F00,F01,F02,F03,F04,F05,F06,F07);
    ISSG(1, F10,F11,F12,F13,F14,F15,F16,F17);

    sync_stage_h(flags, tag, wg, tid, h2buf, xs); ++tag;
    float g0=0.f, g1=0.f, g2=0.f, g3=0.f;
    DC(F00,0,g0); DC(F01,1,g0); DC(F02,2,g0); DC(F03,3,g0);
    DC(F04,4,g0); DC(F05,5,g0); DC(F06,6,g0); DC(F07,7,g0);
    DC(F10,0,g1); DC(F11,1,g1); DC(F12,2,g1); DC(F13,3,g1);
    DC(F14,4,g1); DC(F15,5,g1); DC(F16,6,g1); DC(F17,7,g1);
    ISSG(2, F00,F01,F02,F03,F04,F05,F06,F07);
    ISSG(3, F10,F11,F12,F13,F14,F15,F16,F17);
    s0=0.f; s1=0.f;
    DR2(0, D00, D10); DR2(1, D01, D11); DR2(2, D02, D12); DR2(3, D03, D13);
    DR2(4, D04, D14); DR2(5, D05, D15); DR2(6, D06, D16); DR2(7, D07, D17);
    wait_vm0();
    DC(F00,0,g2); DC(F01,1,g2); DC(F02,2,g2); DC(F03,3,g2);
    DC(F04,4,g2); DC(F05,5,g2); DC(F06,6,g2); DC(F07,7,g2);
    DC(F10,0,g3); DC(F11,1,g3); DC(F12,2,g3); DC(F13,3,g3);
    DC(F14,4,g3); DC(F15,5,g3); DC(F16,6,g3); DC(F17,7,g3);
    g0 = wred(g0); g1 = wred(g1); g2 = wred(g2); g3 = wred(g3);
    s0 = wred(s0); s1 = wred(s1);
    u0 += dt * (g0 + c0); u1 += dt * (g1 + c1);
    u2 += dt * (g2 + c2); u3 += dt * (g3 + c3);
    yv0 += dt * (s0 + b30); yv1 += dt * (s1 + b31);
    float* yout = out + (size_t)step * NDATA;
    if (lane == 0) {
      f32x2 yv; yv.x = yv0; yv.y = yv1;
      st_sc_x2(yout + rf, yv);
      u32x2 xv;
      xv.x = pk_bf16(sp_f(u0 + b00), sp_f(u1 + b01));
      xv.y = pk_bf16(sp_f(u2 + b02), sp_f(u3 + b03));
      st_sc_u2(x1buf + (rw >> 1), xv);
    }
    wait_vm0();
  }
}

// ======================================================================
// FALLBACK A (ws fits bf16 but not G): round-14 kernel, verbatim.
// ======================================================================

__global__ void __launch_bounds__(TPB_R, 1) ode_res(
    const float* __restrict__ ts, const float* __restrict__ y0,
    const u32x4* __restrict__ W0p, const float* __restrict__ b0,
    const u32x4* __restrict__ W1p, const float* __restrict__ b1,
    const u32x4* __restrict__ W2p, const float* __restrict__ b2,
    const u32x4* __restrict__ W3p, const float* __restrict__ b3,
    float* __restrict__ out, uint* hA, uint* hB,
    uint* flags)
{
  __shared__ u32x4 W1lds[16 * 512];
  __shared__ uint xs[2048];
  const int wg = blockIdx.x, tid = threadIdx.x;
  const int wave = tid >> 6, lane = tid & 63;
  const float dt = ts[1] - ts[0];
  const int rw = wg * 16 + wave * 4;
  const int rf = wg * 8 + wave * 2;
  const u32x2* xw2 = (const u32x2*)xs;
  const u32x4* w1p = &W1lds[(wave * 4) * 512];

#pragma unroll
  for (int k = 0; k < 32; ++k)
    W1lds[k * 256 + tid] = W1p[(size_t)wg * 8192 + k * 256 + tid];

  u32x4 C00=L2W(0,0),C01=L2W(0,1),C02=L2W(0,2),C03=L2W(0,3),C04=L2W(0,4),C05=L2W(0,5),C06=L2W(0,6),C07=L2W(0,7);
  u32x4 C10=L2W(1,0),C11=L2W(1,1),C12=L2W(1,2),C13=L2W(1,3),C14=L2W(1,4),C15=L2W(1,5),C16=L2W(1,6),C17=L2W(1,7);
  u32x4 C20=L2W(2,0),C21=L2W(2,1),C22=L2W(2,2),C23=L2W(2,3),C24=L2W(2,4),C25=L2W(2,5),C26=L2W(2,6),C27=L2W(2,7);
  u32x4 C30=L2W(3,0),C31=L2W(3,1),C32=L2W(3,2),C33=L2W(3,3),C34=L2W(3,4),C35=L2W(3,5),C36=L2W(3,6),C37=L2W(3,7);
  u32x4 D00=L3W(0,0),D01=L3W(0,1),D02=L3W(0,2),D03=L3W(0,3),D04=L3W(0,4),D05=L3W(0,5),D06=L3W(0,6),D07=L3W(0,7);
  u32x4 D10=L3W(1,0),D11=L3W(1,1),D12=L3W(1,2),D13=L3W(1,3),D14=L3W(1,4),D15=L3W(1,5),D16=L3W(1,6),D17=L3W(1,7);

  const float b00=SREG(b0[rw]), b01=SREG(b0[rw+1]), b02=SREG(b0[rw+2]), b03=SREG(b0[rw+3]);
  const float b10=SREG(b1[rw]), b11=SREG(b1[rw+1]), b12=SREG(b1[rw+2]), b13=SREG(b1[rw+3]);
  const float b20=SREG(b2[rw]), b21=SREG(b2[rw+1]), b22=SREG(b2[rw+2]), b23=SREG(b2[rw+3]);
  const float b30=SREG(b3[rf]), b31=SREG(b3[rf+1]);

  wait_vm0(); wait_lgkm0();
  wgbar();

  const u32x4* w0base = W0p + (size_t)rw * 256 + lane;
#define ISSW0(r, Qa, Qb, Qc, Qd) do{ const u32x4* p_ = w0base + (size_t)(r)*256; \
  ld_g(p_, Qa); ld_g(p_+64, Qb); ld_g(p_+128, Qc); ld_g(p_+192, Qd); }while(0)

  u32x4 E0a,E0b,E0c,E0d, E1a,E1b,E1c,E1d, E2a,E2b,E2c,E2d, E3a,E3b,E3c,E3d;
  ISSW0(0, E0a,E0b,E0c,E0d);

  uint tag = 0;
  const float* yin = y0;
  for (int step = 0; step < NSTEP; ++step) {
    float s0, s1, s2, s3;
    sync_stage_y(flags, tag, wg, tid, yin, xs); ++tag;
    ISSW0(1, E1a,E1b,E1c,E1d);
    s0 = 0.f; DC(E0a,0,s0); DC(E0b,1,s0); DC(E0c,2,s0); DC(E0d,3,s0);
    ISSW0(2, E2a,E2b,E2c,E2d);
    wait_vmN<4>();
    s1 = 0.f; DC(E1a,0,s1); DC(E1b,1,s1); DC(E1c,2,s1); DC(E1d,3,s1);
    ISSW0(3, E3a,E3b,E3c,E3d);
    wait_vmN<4>();
    s2 = 0.f; DC(E2a,0,s2); DC(E2b,1,s2); DC(E2c,2,s2); DC(E2d,3,s2);
    wait_vm0();
    s3 = 0.f; DC(E3a,0,s3); DC(E3b,1,s3); DC(E3c,2,s3); DC(E3d,3,s3);
    s0 = wred(s0); s1 = wred(s1); s2 = wred(s2); s3 = wred(s3);
    if (lane == 0) {
      u32x2 v; v.x = pk_bf16(sp_f(s0+b00), sp_f(s1+b01));
               v.y = pk_bf16(sp_f(s2+b02), sp_f(s3+b03));
      st_sc_u2(hA + (rw >> 1), v);
    }
    wait_vm0();

    sync_stage_h(flags, tag, wg, tid, hA, xs); ++tag;
    s0=0.f; s1=0.f; s2=0.f; s3=0.f;
    DL4(0); DL4(1); DL4(2); DL4(3); DL4(4); DL4(5); DL4(6); DL4(7);
    s0 = wred(s0); s1 = wred(s1); s2 = wred(s2); s3 = wred(s3);
    if (lane == 0) {
      u32x2 v; v.x = pk_bf16(sp_f(s0+b10), sp_f(s1+b11));
               v.y = pk_bf16(sp_f(s2+b12), sp_f(s3+b13));
      st_sc_u2(hB + (rw >> 1), v);
    }
    wait_vm0();

    sync_stage_h(flags, tag, wg, tid, hB, xs); ++tag;
    s0=0.f; s1=0.f; s2=0.f; s3=0.f;
    DR4(0, C00, C10, C20, C30); DR4(1, C01, C11, C21, C31);
    DR4(2, C02, C12, C22, C32); DR4(3, C03, C13, C23, C33);
    DR4(4, C04, C14, C24, C34); DR4(5, C05, C15, C25, C35);
    DR4(6, C06, C16, C26, C36); DR4(7, C07, C17, C27, C37);
    s0 = wred(s0); s1 = wred(s1); s2 = wred(s2); s3 = wred(s3);
    if (lane == 0) {
      u32x2 v; v.x = pk_bf16(sp_f(s0+b20), sp_f(s1+b21));
               v.y = pk_bf16(sp_f(s2+b22), sp_f(s3+b23));
      st_sc_u2(hA + (rw >> 1), v);
    }
    wait_vm0();

    sync_stage_h(flags, tag, wg, tid, hA, xs); ++tag;
    f32x2 yo;
    ld_sc_x2_issue(yin + rf, yo);
    s0=0.f; s1=0.f;
    DR2(0, D00, D10); DR2(1, D01, D11); DR2(2, D02, D12); DR2(3, D03, D13);
    DR2(4, D04, D14); DR2(5, D05, D15); DR2(6, D06, D16); DR2(7, D07, D17);
    s0 = wred(s0); s1 = wred(s1);
    wait_vm0();
    float* yout = out + (size_t)step * NDATA;
    if (lane == 0) {
      f32x2 v; v.x = yo.x + dt * (s0 + b30); v.y = yo.y + dt * (s1 + b31);
      st_sc_x2(yout + rf, v);
    }
    ISSW0(0, E0a,E0b,E0c,E0d);
    wait_vmN<4>();
    yin = yout;
  }
}

// ======================================================================
// FALLBACK B (ws tiny): fp32 streaming kernel, TPB=1024.
// ======================================================================

__device__ __forceinline__ void gbar1k(uint* flags, uint tag, int wg, int tid) {
  wgbar();
  if (tid == 0) st_sc_u32(flags + wg * 16, tag);
  if (tid < NWG) {
    const uint* fp = flags + tid * 16;
    if (ld_sc_u32(fp) < tag) {
      do { __builtin_amdgcn_s_sleep(1); } while (ld_sc_u32(fp) < tag);
    }
  }
  wgbar();
}

__device__ __forceinline__ void stage4096_1k(const float* src, float* xsf, int tid) {
  f32x4 a;
  ld_sc_x4_issue((const f32x4*)src + tid, a);
  wait_vm0();
  ((f32x4*)xsf)[tid] = a;
  wait_lgkm0();
  wgbar();
}
__device__ __forceinline__ void stage2048_1k(const float* src, float* xsf, int tid) {
  f32x4 a;
  bool act = tid < 512;
  if (act) ld_sc_x4_issue((const f32x4*)src + tid, a);
  wait_vm0();
  if (act) ((f32x4*)xsf)[tid] = a;
  wait_lgkm0();
  wgbar();
}

__device__ __forceinline__ void issue_row_f32(const float* W, size_t elemidx, int lane, f32x4* wr, int ni) {
  const f32x4* p = (const f32x4*)(W + elemidx) + lane;
  for (int i = 0; i < ni; ++i)
    asm volatile("global_load_dwordx4 %0, %1, off" : "=v"(wr[i]) : "v"(p + i * 64) : "memory");
}

template<int NI>
__device__ __forceinline__ float dot_row_f32(const f32x4* wr, const float* xsf, int xoff, int lane) {
  const f32x4* x4 = (const f32x4*)xsf + xoff;
  float a = 0.f;
#pragma unroll
  for (int i = 0; i < NI; ++i) {
    f32x4 xv = x4[i * 64 + lane];
    a = fmaf(wr[i].x, xv.x, a); a = fmaf(wr[i].y, xv.y, a);
    a = fmaf(wr[i].z, xv.z, a); a = fmaf(wr[i].w, xv.w, a);
  }
  return a;
}

__global__ void __launch_bounds__(TPB_S, 1) ode_stream(
    const float* __restrict__ ts, const float* __restrict__ y0,
    const float* __restrict__ W0, const float* __restrict__ b0,
    const float* __restrict__ W1, const float* __restrict__ b1,
    const float* __restrict__ W2, const float* __restrict__ b2,
    const float* __restrict__ W3, const float* __restrict__ b3,
    float* __restrict__ out, float* hA, float* hB,
    uint* flags)
{
  __shared__ float xsf[WIDTH];
  __shared__ float ps[16];
  const int wg = blockIdx.x, tid = threadIdx.x;
  const int wave = tid >> 6, lane = tid & 63;
  const float dt = ts[1] - ts[0];
  const int rw = wg * 16 + wave;
  const int rF = wg * 8 + (wave >> 1);
  const int hf = wave & 1;

  f32x4 w0r[8], w1r[16], w2r[16], w3r[8];
  issue_row_f32(W0, (size_t)rw * NDATA, lane, w0r, 8);

  uint tag = 0;
  const float* yin = y0;
  for (int step = 0; step < NSTEP; ++step) {
    stage2048_1k(yin, xsf, tid);
    float a = wred(dot_row_f32<8>(w0r, xsf, 0, lane));
    if (lane == 0) st_sc_x1(hA + rw, sp_f(a + b0[rw]));
    issue_row_f32(W1, (size_t)rw * WIDTH, lane, w1r, 16);
    wait_vmN<16>();
    gbar1k(flags, ++tag, wg, tid);

    stage4096_1k(hA, xsf, tid);
    a = wred(dot_row_f32<16>(w1r, xsf, 0, lane));
    if (lane == 0) st_sc_x1(hB + rw, sp_f(a + b1[rw]));
    issue_row_f32(W2, (size_t)rw * WIDTH, lane, w2r, 16);
    wait_vmN<16>();
    gbar1k(flags, ++tag, wg, tid);

    stage4096_1k(hB, xsf, tid);
    a = wred(dot_row_f32<16>(w2r, xsf, 0, lane));
    if (lane == 0) st_sc_x1(hA + rw, sp_f(a + b2[rw]));
    issue_row_f32(W3, (size_t)rF * WIDTH + (size_t)hf * 2048, lane, w3r, 8);
    wait_vmN<8>();
    gbar1k(flags, ++tag, wg, tid);

    stage4096_1k(hA, xsf, tid);
    float yo;
    ld_sc_x1_issue(yin + rF, yo);
    a = wred(dot_row_f32<8>(w3r, xsf, hf * 512, lane));
    if (lane == 0) ps[wave] = a;
    wait_lgkm0();
    wgbar();
    wait_vm0();
    float* yout = out + (size_t)step * NDATA;
    if (hf == 0 && lane == 0) {
      float tot = ps[wave] + ps[wave + 1];
      st_sc_x1(yout + rF, yo + dt * (tot + b3[rF]));
    }
    issue_row_f32(W0, (size_t)rw * NDATA, lane, w0r, 8);
    wait_vmN<8>();
    gbar1k(flags, ++tag, wg, tid);
    yin = yout;
  }
}

// ---------- launch ----------

#define WS_X1   0
#define WS_H1   8192
#define WS_H2   16384
#define WS_CNT  32768
#define WS_WB   65536
static const size_t N_W0 = (size_t)WIDTH * NDATA;   // 8.39M elems
static const size_t N_W1 = (size_t)WIDTH * WIDTH;   // 16.78M
static const size_t N_W3 = (size_t)NDATA * WIDTH;   // 8.39M
static const size_t N_G  = (size_t)WIDTH * WIDTH;   // 16.78M

extern "C" void kernel_launch(void* const* d_in, const int* in_sizes, int n_in,
                              void* d_out, int out_size, void* d_ws, size_t ws_size,
                              hipStream_t stream) {
  const float* ts = (const float*)d_in[0];
  const float* y0 = (const float*)d_in[1];
  const float* W0 = (const float*)d_in[2];
  const float* b0 = (const float*)d_in[3];
  const float* W1 = (const float*)d_in[4];
  const float* b1 = (const float*)d_in[5];
  const float* W2 = (const float*)d_in[6];
  const float* b2 = (const float*)d_in[7];
  const float* W3 = (const float*)d_in[8];
  const float* b3 = (const float*)d_in[9];
  float* out = (float*)d_out;

  char* ws = (char*)d_ws;
  uint* flags = (uint*)(ws + WS_CNT);

  hipMemsetAsync(ws + WS_CNT, 0, 16384, stream);

  const size_t need_bf  = WS_WB + (N_W0 + 2 * N_W1 + N_W3) * 2;        // ~100.7 MB
  const size_t need_fus = need_bf + N_G * 2;                           // ~134.2 MB

  u32x4* W0p = (u32x4*)(ws + WS_WB);
  u32x4* W1p = W0p + N_W0 / 8;
  u32x4* W2p = W1p + N_W1 / 8;
  u32x4* W3p = W2p + N_W1 / 8;
  u32x4* Gp  = W3p + N_W3 / 8;

  if (ws_size >= need_fus) {
    hipLaunchKernelGGL(cvt_perm, dim3((unsigned)(N_W0 / 8 / 256)), dim3(256), 0, stream, W0, W0p, WIDTH, NDATA);
    hipLaunchKernelGGL(cvt_perm, dim3((unsigned)(N_W1 / 8 / 256)), dim3(256), 0, stream, W1, W1p, WIDTH, WIDTH);
    hipLaunchKernelGGL(cvt_perm, dim3((unsigned)(N_W1 / 8 / 256)), dim3(256), 0, stream, W2, W2p, WIDTH, WIDTH);
    hipLaunchKernelGGL(cvt_perm, dim3((unsigned)(N_W3 / 8 / 256)), dim3(256), 0, stream, W3, W3p, NDATA, WIDTH);
    hipLaunchKernelGGL(gemm_G2, dim3(2048), dim3(256), 0, stream, W0, W3, (uint*)Gp);
    uint* x1b = (uint*)(ws + WS_X1);
    uint* h1b = (uint*)(ws + WS_H1);
    uint* h2b = (uint*)(ws + WS_H2);
    hipLaunchKernelGGL(ode_fused, dim3(NWG), dim3(TPB_R), 0, stream,
                       ts, y0, W0p, b0, W1p, b1, W2p, b2, W3p, b3, Gp,
                       out, x1b, h1b, h2b, flags);
  } else if (ws_size >= need_bf) {
    hipLaunchKernelGGL(cvt_perm, dim3((unsigned)(N_W0 / 8 / 256)), dim3(256), 0, stream, W0, W0p, WIDTH, NDATA);
    hipLaunchKernelGGL(cvt_perm, dim3((unsigned)(N_W1 / 8 / 256)), dim3(256), 0, stream, W1, W1p, WIDTH, WIDTH);
    hipLaunchKernelGGL(cvt_perm, dim3((unsigned)(N_W1 / 8 / 256)), dim3(256), 0, stream, W2, W2p, WIDTH, WIDTH);
    hipLaunchKernelGGL(cvt_perm, dim3((unsigned)(N_W3 / 8 / 256)), dim3(256), 0, stream, W3, W3p, NDATA, WIDTH);
    uint* hA = (uint*)(ws + WS_X1);
    uint* hB = (uint*)(ws + WS_H2);
    hipLaunchKernelGGL(ode_res, dim3(NWG), dim3(TPB_R), 0, stream,
                       ts, y0, W0p, b0, W1p, b1, W2p, b2, W3p, b3,
                       out, hA, hB, flags);
  } else {
    float* hAf = (float*)(ws + WS_X1);
    float* hBf = (float*)(ws + WS_H2);
    hipLaunchKernelGGL(ode_stream, dim3(NWG), dim3(TPB_S), 0, stream,
                       ts, y0, W0, b0, W1, b1, W2, b2, W3, b3,
                       out, hAf, hBf, flags);
  }
}